// Round 3
// baseline (107.251 us; speedup 1.0000x reference)
//
#include <hip/hip_runtime.h>
#include <hip/hip_bf16.h>
#include <math.h>

constexpr int B_  = 2048;
constexpr int S_  = 16;
constexpr int D_  = 512;
constexpr int CH_ = 1024;

// expert GEMM tiling
constexpr int BM = 64;    // samples
constexpr int BN = 64;    // ch columns
constexpr int BK = 128;   // k per tile (4 tiles over D=512)
constexpr int SA = 136;   // LDS row stride (shorts): 128 + 8 pad -> bank-rotating
constexpr int SB = 136;

typedef __attribute__((ext_vector_type(8))) short bf16x8;
typedef __attribute__((ext_vector_type(4))) float f32x4;

constexpr size_t CNT_OFF  = 0;
constexpr size_t LIST_OFF = 256;

static __device__ __forceinline__ short f2bf(float x) {
    __hip_bfloat16 h = __float2bfloat16(x);
    return *(short*)&h;
}
static __device__ __forceinline__ float gelu_exact(float x) {
    return 0.5f * x * (1.f + erff(x * 0.70710678118654752f));
}

// ---------------- kernel 1: router + log_softmax + argmax + compaction ----------------
__global__ __launch_bounds__(1024) void k_router_sm(
    const float* __restrict__ ldt, const float* __restrict__ ldr,
    const float* __restrict__ w,   const float* __restrict__ bsc,
    float* __restrict__ sld, int* __restrict__ count, int* __restrict__ list)
{
    const int b    = blockIdx.x;
    const int wave = threadIdx.x >> 6;
    const int lane = threadIdx.x & 63;

    __shared__ float lgs[S_];

    const float4* pt = (const float4*)(ldt + ((size_t)b * S_ + wave) * D_);
    const float4* pr = (const float4*)(ldr + ((size_t)b * S_ + wave) * D_);
    const float4* wt = (const float4*)(w);
    const float4* wr = (const float4*)(w + D_);

    float acc = 0.f;
    #pragma unroll
    for (int it = 0; it < 2; it++) {
        const int i = lane + it * 64;
        float4 a  = pt[i]; float4 ww = wt[i];
        acc += a.x * ww.x + a.y * ww.y + a.z * ww.z + a.w * ww.w;
        float4 c  = pr[i]; float4 w2 = wr[i];
        acc += c.x * w2.x + c.y * w2.y + c.z * w2.z + c.w * w2.w;
    }
    #pragma unroll
    for (int off = 32; off > 0; off >>= 1) acc += __shfl_down(acc, off, 64);
    if (lane == 0) lgs[wave] = acc;
    __syncthreads();

    if (threadIdx.x < S_) {
        const int s = threadIdx.x;
        const float v = lgs[s] + bsc[0];
        float mv = v; int mi = s;
        #pragma unroll
        for (int d = 1; d < 16; d <<= 1) {
            float ov = __shfl_xor(mv, d, 16);
            int   oi = __shfl_xor(mi, d, 16);
            if (ov > mv || (ov == mv && oi < mi)) { mv = ov; mi = oi; }
        }
        float sum = expf(v - mv);
        #pragma unroll
        for (int d = 1; d < 16; d <<= 1) sum += __shfl_xor(sum, d, 16);
        const float lse = mv + logf(sum);
        sld[b * S_ + s] = v - lse;
        if (s == 0) {
            const int pos = atomicAdd(&count[mi], 1);
            list[mi * B_ + pos] = b;
        }
    }
}

// ---------------- kernel 2: expert heads, pipelined MFMA grouped GEMM ----------------
// bid = (((m*2+head) * 32 + st) * 16) + ct   (ct innermost: x reuse + st-partners same XCD)
__global__ __launch_bounds__(256) void k_expert_mfma(
    const float* __restrict__ ldt, const float* __restrict__ ldr,
    const float* __restrict__ Wht, const float* __restrict__ bht,
    const float* __restrict__ Wot, const float* __restrict__ bot,
    const float* __restrict__ Whr, const float* __restrict__ bhr,
    const float* __restrict__ Wor, const float* __restrict__ bor,
    const int* __restrict__ count, const int* __restrict__ list,
    float* __restrict__ pose)
{
    const int bid  = blockIdx.x;
    const int ct   = bid & 15;
    const int st   = (bid >> 4) & 31;
    const int head = (bid >> 9) & 1;
    const int m    = bid >> 10;

    const int n = count[m];
    if (st * BM >= n) return;

    const float* __restrict__ xsrc = head ? ldr : ldt;
    const float* __restrict__ Wh   = head ? Whr : Wht;
    const float* __restrict__ bh   = head ? bhr : bht;
    const float* __restrict__ Wo   = head ? Wor : Wot;
    const float* __restrict__ bo   = head ? bor : bot;
    const int noj    = head ? 4 : 3;
    const int jobase = head ? 3 : 0;
    const int ch0    = ct * BN;

    __shared__ short As[BM * SA];   // 17 KB
    __shared__ short Bs[BN * SB];   // 17 KB
    __shared__ int   bidx[BM];

    const int tid  = threadIdx.x;
    const int wave = tid >> 6;
    const int lane = tid & 63;
    const int wr   = wave >> 1;
    const int wc   = wave & 1;
    const int rbase = wr * 32;
    const int cbase = wc * 32;

    if (tid < BM) {
        const int gi = st * BM + tid;
        bidx[tid] = (gi < n) ? list[m * B_ + gi] : -1;
    }
    __syncthreads();

    // per-thread staging geometry
    const int rA = tid >> 2;          // A row (sample slot)
    const int kq = tid & 3;           // A k-quarter (32 k each)
    const int bb = bidx[rA];
    const float* xrow = (bb >= 0) ? (xsrc + ((size_t)bb * S_ + m) * D_) : nullptr;

    const int u2  = tid >> 5;         // 0..7  (B k-chunk group; uniform per half-wave)
    const int chb = tid & 31;         // B ch within tile
    const float* wcol = Wh + (size_t)m * D_ * CH_ + ch0 + chb;

    auto loadA = [&](float4* pa, int t) {
        if (bb >= 0) {
            const float4* p = (const float4*)(xrow + t * BK) + kq * 8;
            #pragma unroll
            for (int i = 0; i < 8; i++) pa[i] = p[i];
        } else {
            #pragma unroll
            for (int i = 0; i < 8; i++) pa[i] = make_float4(0.f, 0.f, 0.f, 0.f);
        }
    };
    auto loadB = [&](float* pb, int t) {
        #pragma unroll
        for (int i = 0; i < 4; i++) {
            const int uu = u2 * 2 + (i >> 1);
            const float* p = wcol + (size_t)(t * BK + uu * 8) * CH_ + (i & 1) * 32;
            #pragma unroll
            for (int j = 0; j < 8; j++) pb[i * 8 + j] = p[(size_t)j * CH_];
        }
    };
    auto storeTiles = [&](const float4* pa, const float* pb) {
        #pragma unroll
        for (int c = 0; c < 4; c++) {
            short tmp[8];
            const float4 v0 = pa[c * 2], v1 = pa[c * 2 + 1];
            tmp[0]=f2bf(v0.x); tmp[1]=f2bf(v0.y); tmp[2]=f2bf(v0.z); tmp[3]=f2bf(v0.w);
            tmp[4]=f2bf(v1.x); tmp[5]=f2bf(v1.y); tmp[6]=f2bf(v1.z); tmp[7]=f2bf(v1.w);
            *(bf16x8*)&As[rA * SA + kq * 32 + c * 8] = *(bf16x8*)tmp;
        }
        #pragma unroll
        for (int i = 0; i < 4; i++) {
            const int uu = u2 * 2 + (i >> 1);
            const int ch = chb + (i & 1) * 32;
            short tmp[8];
            #pragma unroll
            for (int j = 0; j < 8; j++) tmp[j] = f2bf(pb[i * 8 + j]);
            *(bf16x8*)&Bs[ch * SB + uu * 8] = *(bf16x8*)tmp;
        }
    };

    f32x4 acc[2][2] = {};
    auto mfmaTile = [&]() {
        #pragma unroll
        for (int kk = 0; kk < 4; kk++) {
            const int ub = kk * 4 + (lane >> 4);
            bf16x8 af[2], bfv[2];
            #pragma unroll
            for (int fm = 0; fm < 2; fm++)
                af[fm] = *(bf16x8*)&As[(rbase + fm * 16 + (lane & 15)) * SA + ub * 8];
            #pragma unroll
            for (int fn = 0; fn < 2; fn++)
                bfv[fn] = *(bf16x8*)&Bs[(cbase + fn * 16 + (lane & 15)) * SB + ub * 8];
            #pragma unroll
            for (int fm = 0; fm < 2; fm++)
                #pragma unroll
                for (int fn = 0; fn < 2; fn++)
                    acc[fm][fn] = __builtin_amdgcn_mfma_f32_16x16x32_bf16(af[fm], bfv[fn], acc[fm][fn], 0, 0, 0);
        }
    };

    // pipelined main loop over 4 k-tiles: prefetch t+1 during MFMA(t)
    float4 pa[8], qa[8];
    float  pb[32], qb[32];
    loadA(pa, 0); loadB(pb, 0);

    storeTiles(pa, pb); __syncthreads();
    loadA(qa, 1); loadB(qb, 1);
    mfmaTile(); __syncthreads();

    storeTiles(qa, qb); __syncthreads();
    loadA(pa, 2); loadB(pb, 2);
    mfmaTile(); __syncthreads();

    storeTiles(pa, pb); __syncthreads();
    loadA(qa, 3); loadB(qb, 3);
    mfmaTile(); __syncthreads();

    storeTiles(qa, qb); __syncthreads();
    mfmaTile(); __syncthreads();

    // ---- epilogue: bias + GELU + Wo partial + 16-lane reduce + atomicAdd ----
    float g[2][2][4];
    float wo_l[2][4];
    #pragma unroll
    for (int fn = 0; fn < 2; fn++) {
        const int ch = ch0 + cbase + fn * 16 + (lane & 15);
        const float bias = bh[m * CH_ + ch];
        #pragma unroll
        for (int fm = 0; fm < 2; fm++)
            #pragma unroll
            for (int j = 0; j < 4; j++)
                g[fm][fn][j] = gelu_exact(acc[fm][fn][j] + bias);
        #pragma unroll
        for (int jo = 0; jo < 4; jo++)
            wo_l[fn][jo] = (jo < noj) ? Wo[(size_t)(m * CH_ + ch) * noj + jo] : 0.f;
    }

    #pragma unroll
    for (int fm = 0; fm < 2; fm++) {
        #pragma unroll
        for (int j = 0; j < 4; j++) {
            const int lr = rbase + fm * 16 + ((lane >> 4) << 2) + j;
            const int bb2 = bidx[lr];
            #pragma unroll
            for (int jo = 0; jo < 4; jo++) {
                if (jo >= noj) continue;
                float v = g[fm][0][j] * wo_l[0][jo] + g[fm][1][j] * wo_l[1][jo];
                #pragma unroll
                for (int d = 1; d < 16; d <<= 1) v += __shfl_xor(v, d, 16);
                if ((lane & 15) == 0 && bb2 >= 0) {
                    if (ct == 0 && wc == 0) v += bo[m * noj + jo];
                    atomicAdd(&pose[(size_t)bb2 * 7 + jobase + jo], v);
                }
            }
        }
    }
}

// ---------------- launch ----------------
extern "C" void kernel_launch(void* const* d_in, const int* in_sizes, int n_in,
                              void* d_out, int out_size, void* d_ws, size_t ws_size,
                              hipStream_t stream)
{
    const float* ldt = (const float*)d_in[0];
    const float* ldr = (const float*)d_in[1];
    const float* wsc = (const float*)d_in[2];
    const float* bsc = (const float*)d_in[3];
    const float* Wht = (const float*)d_in[4];
    const float* bht = (const float*)d_in[5];
    const float* Wot = (const float*)d_in[6];
    const float* bot = (const float*)d_in[7];
    const float* Whr = (const float*)d_in[8];
    const float* bhr = (const float*)d_in[9];
    const float* Wor = (const float*)d_in[10];
    const float* bor = (const float*)d_in[11];

    float* pose = (float*)d_out;                   // [B,7]
    float* sld  = (float*)d_out + (size_t)B_ * 7;  // [B,16]

    int* count = (int*)((char*)d_ws + CNT_OFF);
    int* list  = (int*)((char*)d_ws + LIST_OFF);

    hipMemsetAsync(count, 0, 16 * sizeof(int), stream);
    hipMemsetAsync(pose, 0, (size_t)B_ * 7 * sizeof(float), stream);

    k_router_sm<<<dim3(B_), dim3(1024), 0, stream>>>(ldt, ldr, wsc, bsc, sld, count, list);

    // grid = m(16) x head(2) x st(32) x ct(16), ct innermost
    k_expert_mfma<<<dim3(16 * 2 * 32 * 16), dim3(256), 0, stream>>>(
        ldt, ldr, Wht, bht, Wot, bot, Whr, bhr, Wor, bor, count, list, pose);
}